// Round 5
// baseline (524.280 us; speedup 1.0000x reference)
//
#include <hip/hip_runtime.h>
#include <math.h>

#define N_LAYERS 5
#define NG 20

// ---------------------------------------------------------------------------
// Fully fused kernel. Per block:
//   phase 1: lanes 0..19 build the 20 shared U3 gate matrices into LDS g[][].
//   phase 2: lanes 0..15 propagate basis column t through 5 layers + ring
//            CNOTs -> 16x16 complex unitary W, written to LDS row-major
//            interleaved (re,im): Ws[j*32 + 2k {,+1}] = W[j][k].
//   phase 3: every thread processes TWO samples (ILP: two independent FMA
//            chains), reading W rows as wave-uniform ds_read_b128 broadcasts.
//            <Z_i> accumulated on the fly with compile-time signs.
// ---------------------------------------------------------------------------
__device__ __forceinline__ void encode_psi0(const float4 xv,
                                            float* __restrict__ sr,
                                            float* __restrict__ si) {
    const float xs[4] = {xv.x, xv.y, xv.z, xv.w};
    float vr[4][2], vi[4][2];
#pragma unroll
    for (int i = 0; i < 4; i++) {
        float st, ct, sx, cx;
        __sincosf(xs[i] * 0.5f, &st, &ct);
        __sincosf(xs[i], &sx, &cx);
        vr[i][0] = ct;      vi[i][0] = 0.0f;
        vr[i][1] = cx * st; vi[i][1] = sx * st;
    }
    float w01r[4], w01i[4], w23r[4], w23i[4];
#pragma unroll
    for (int a = 0; a < 2; a++) {
#pragma unroll
        for (int c = 0; c < 2; c++) {
            w01r[a * 2 + c] = vr[0][a] * vr[1][c] - vi[0][a] * vi[1][c];
            w01i[a * 2 + c] = vr[0][a] * vi[1][c] + vi[0][a] * vr[1][c];
            w23r[a * 2 + c] = vr[2][a] * vr[3][c] - vi[2][a] * vi[3][c];
            w23i[a * 2 + c] = vr[2][a] * vi[3][c] + vi[2][a] * vr[3][c];
        }
    }
#pragma unroll
    for (int hi = 0; hi < 4; hi++) {
#pragma unroll
        for (int lo = 0; lo < 4; lo++) {
            sr[hi * 4 + lo] = w01r[hi] * w23r[lo] - w01i[hi] * w23i[lo];
            si[hi * 4 + lo] = w01r[hi] * w23i[lo] + w01i[hi] * w23r[lo];
        }
    }
}

__global__ __launch_bounds__(256, 4) void qfused(const float* __restrict__ x,
                                                 const float* __restrict__ w,
                                                 float* __restrict__ out) {
    __shared__ float g[NG][8];
    __shared__ float Ws[512];
    const int t = threadIdx.x;

    // --- phase 1: gate matrices ---
    if (t < NG) {
        float th = w[t * 3 + 0], ph = w[t * 3 + 1], la = w[t * 3 + 2];
        float st, ct, sl, cl, sp, cp, spl, cpl;
        __sincosf(th * 0.5f, &st, &ct);
        __sincosf(la, &sl, &cl);
        __sincosf(ph, &sp, &cp);
        __sincosf(ph + la, &spl, &cpl);
        g[t][0] = ct;        g[t][1] = 0.0f;
        g[t][2] = -cl * st;  g[t][3] = -sl * st;
        g[t][4] = cp * st;   g[t][5] = sp * st;
        g[t][6] = cpl * ct;  g[t][7] = spl * ct;
    }
    __syncthreads();

    // --- phase 2: compose W (lanes 0..15 of wave 0; verified R1/R2 code) ---
    if (t < 16) {
        float ar[16], ai[16];
#pragma unroll
        for (int i = 0; i < 16; i++) { ar[i] = 0.0f; ai[i] = 0.0f; }
        ar[t] = 1.0f;
#pragma unroll
        for (int l = 0; l < N_LAYERS; l++) {
#pragma unroll
            for (int wi = 0; wi < 4; wi++) {
                const float* gm = g[l * 4 + wi];
                const float m00r = gm[0];
                const float m01r = gm[2], m01i = gm[3];
                const float m10r = gm[4], m10i = gm[5];
                const float m11r = gm[6], m11i = gm[7];
                const int stride = 8 >> wi;
#pragma unroll
                for (int base = 0; base < 16; base++) {
                    if (base & stride) continue;
                    const int i1 = base + stride;
                    const float s0r = ar[base], s0i = ai[base];
                    const float s1r = ar[i1],   s1i = ai[i1];
                    ar[base] = m00r * s0r + m01r * s1r - m01i * s1i;
                    ai[base] = m00r * s0i + m01r * s1i + m01i * s1r;
                    ar[i1]   = m10r * s0r - m10i * s0i + m11r * s1r - m11i * s1i;
                    ai[i1]   = m10r * s0i + m10i * s0r + m11r * s1i + m11i * s1r;
                }
            }
            const int ringc[4] = {0, 1, 2, 3};
            const int ringt[4] = {1, 2, 3, 0};
#pragma unroll
            for (int e = 0; e < 4; e++) {
                const int cm = 8 >> ringc[e];
                const int tm = 8 >> ringt[e];
#pragma unroll
                for (int idx = 0; idx < 16; idx++) {
                    if ((idx & cm) && !(idx & tm)) {
                        const int j = idx | tm;
                        float tr = ar[idx]; ar[idx] = ar[j]; ar[j] = tr;
                        float ti = ai[idx]; ai[idx] = ai[j]; ai[j] = ti;
                    }
                }
            }
        }
#pragma unroll
        for (int j = 0; j < 16; j++) {
            Ws[j * 32 + 2 * t]     = ar[j];
            Ws[j * 32 + 2 * t + 1] = ai[j];
        }
    }
    __syncthreads();

    // --- phase 3: two samples per thread ---
    const int b0 = blockIdx.x * 512 + t;
    const int b1 = b0 + 256;
    const float4 xa = ((const float4*)x)[b0];
    const float4 xb = ((const float4*)x)[b1];

    float sAr[16], sAi[16], sBr[16], sBi[16];
    encode_psi0(xa, sAr, sAi);
    encode_psi0(xb, sBr, sBi);

    float zA0 = 0.f, zA1 = 0.f, zA2 = 0.f, zA3 = 0.f;
    float zB0 = 0.f, zB1 = 0.f, zB2 = 0.f, zB3 = 0.f;

#pragma unroll
    for (int j = 0; j < 16; j++) {
        const float4* row = (const float4*)(Ws + j * 32);
        float prA0 = 0.f, prA1 = 0.f, piA0 = 0.f, piA1 = 0.f;
        float prB0 = 0.f, prB1 = 0.f, piB0 = 0.f, piB1 = 0.f;
#pragma unroll
        for (int kk = 0; kk < 8; kk++) {
            const float4 q = row[kk];  // (Wr[2kk], Wi[2kk], Wr[2kk+1], Wi[2kk+1])
            const int k = kk * 2;
            prA0 = fmaf(q.x, sAr[k], prA0);
            prA0 = fmaf(-q.y, sAi[k], prA0);
            piA0 = fmaf(q.x, sAi[k], piA0);
            piA0 = fmaf(q.y, sAr[k], piA0);
            prB0 = fmaf(q.x, sBr[k], prB0);
            prB0 = fmaf(-q.y, sBi[k], prB0);
            piB0 = fmaf(q.x, sBi[k], piB0);
            piB0 = fmaf(q.y, sBr[k], piB0);
            prA1 = fmaf(q.z, sAr[k + 1], prA1);
            prA1 = fmaf(-q.w, sAi[k + 1], prA1);
            piA1 = fmaf(q.z, sAi[k + 1], piA1);
            piA1 = fmaf(q.w, sAr[k + 1], piA1);
            prB1 = fmaf(q.z, sBr[k + 1], prB1);
            prB1 = fmaf(-q.w, sBi[k + 1], prB1);
            piB1 = fmaf(q.z, sBi[k + 1], piB1);
            piB1 = fmaf(q.w, sBr[k + 1], piB1);
        }
        const float prA = prA0 + prA1, piA = piA0 + piA1;
        const float prB = prB0 + prB1, piB = piB0 + piB1;
        const float pA = prA * prA + piA * piA;
        const float pB = prB * prB + piB * piB;
        // compile-time signs: wire i flips on bit (8>>i)
        zA0 = (j & 8) ? (zA0 - pA) : (zA0 + pA);
        zA1 = (j & 4) ? (zA1 - pA) : (zA1 + pA);
        zA2 = (j & 2) ? (zA2 - pA) : (zA2 + pA);
        zA3 = (j & 1) ? (zA3 - pA) : (zA3 + pA);
        zB0 = (j & 8) ? (zB0 - pB) : (zB0 + pB);
        zB1 = (j & 4) ? (zB1 - pB) : (zB1 + pB);
        zB2 = (j & 2) ? (zB2 - pB) : (zB2 + pB);
        zB3 = (j & 1) ? (zB3 - pB) : (zB3 + pB);
    }

    ((float4*)out)[b0] = make_float4(zA0, zA1, zA2, zA3);
    ((float4*)out)[b1] = make_float4(zB0, zB1, zB2, zB3);
}

extern "C" void kernel_launch(void* const* d_in, const int* in_sizes, int n_in,
                              void* d_out, int out_size, void* d_ws, size_t ws_size,
                              hipStream_t stream) {
    const float* x = (const float*)d_in[0];   // [B,4] fp32
    const float* w = (const float*)d_in[1];   // [5,4,3] fp32
    float* out = (float*)d_out;               // [B,4] fp32
    const int b = in_sizes[0] / 4;
    qfused<<<b / 512, 256, 0, stream>>>(x, w, out);
}

// Round 6
// 82.240 us; speedup vs baseline: 6.3750x; 6.3750x over previous
//
#include <hip/hip_runtime.h>
#include <math.h>

#define N_LAYERS 5
#define NG 20

// ---------------------------------------------------------------------------
// Pre-kernel: compose the 20 shared U3 gates + ring CNOTs into one 16x16
// complex unitary W, stored interleaved (re,im): W[(j*16+k)*2 + {0,1}]
// = <j| U |k>. One wave; thread k (k<16) propagates basis column e_k.
// (Verified in R1-R4.)
// ---------------------------------------------------------------------------
__global__ __launch_bounds__(64) void compose_W(const float* __restrict__ w,
                                                float* __restrict__ W) {
    __shared__ float g[NG][8];
    const int t = threadIdx.x;
    if (t < NG) {
        float th = w[t * 3 + 0], ph = w[t * 3 + 1], la = w[t * 3 + 2];
        float st, ct, sl, cl, sp, cp, spl, cpl;
        sincosf(th * 0.5f, &st, &ct);
        sincosf(la, &sl, &cl);
        sincosf(ph, &sp, &cp);
        sincosf(ph + la, &spl, &cpl);
        g[t][0] = ct;        g[t][1] = 0.0f;
        g[t][2] = -cl * st;  g[t][3] = -sl * st;
        g[t][4] = cp * st;   g[t][5] = sp * st;
        g[t][6] = cpl * ct;  g[t][7] = spl * ct;
    }
    __syncthreads();
    if (t >= 16) return;

    float ar[16], ai[16];
#pragma unroll
    for (int i = 0; i < 16; i++) { ar[i] = 0.0f; ai[i] = 0.0f; }
    ar[t] = 1.0f;

#pragma unroll
    for (int l = 0; l < N_LAYERS; l++) {
#pragma unroll
        for (int wi = 0; wi < 4; wi++) {
            const float* gm = g[l * 4 + wi];
            const float m00r = gm[0];
            const float m01r = gm[2], m01i = gm[3];
            const float m10r = gm[4], m10i = gm[5];
            const float m11r = gm[6], m11i = gm[7];
            const int stride = 8 >> wi;
#pragma unroll
            for (int base = 0; base < 16; base++) {
                if (base & stride) continue;
                const int i1 = base + stride;
                const float s0r = ar[base], s0i = ai[base];
                const float s1r = ar[i1],   s1i = ai[i1];
                ar[base] = m00r * s0r + m01r * s1r - m01i * s1i;
                ai[base] = m00r * s0i + m01r * s1i + m01i * s1r;
                ar[i1]   = m10r * s0r - m10i * s0i + m11r * s1r - m11i * s1i;
                ai[i1]   = m10r * s0i + m10i * s0r + m11r * s1i + m11i * s1r;
            }
        }
        const int ringc[4] = {0, 1, 2, 3};
        const int ringt[4] = {1, 2, 3, 0};
#pragma unroll
        for (int e = 0; e < 4; e++) {
            const int cm = 8 >> ringc[e];
            const int tm = 8 >> ringt[e];
#pragma unroll
            for (int idx = 0; idx < 16; idx++) {
                if ((idx & cm) && !(idx & tm)) {
                    const int j = idx | tm;
                    float tr = ar[idx]; ar[idx] = ar[j]; ar[j] = tr;
                    float ti = ai[idx]; ai[idx] = ai[j]; ai[j] = ti;
                }
            }
        }
    }
#pragma unroll
    for (int j = 0; j < 16; j++) {
        W[(j * 16 + t) * 2 + 0] = ar[j];
        W[(j * 16 + t) * 2 + 1] = ai[j];
    }
}

// ---------------------------------------------------------------------------
// Main kernel: R2 structure (1 sample/thread, everything inline — proven
// spill-free) with ONE change: W rows read as 8x float4 broadcasts
// (global_load_dwordx4, L1-resident) instead of 512 scalar dwords.
// VMEM wave-instrs per CU drop 4x below the VALU floor.
// ---------------------------------------------------------------------------
__global__ __launch_bounds__(256, 4) void qmain(const float* __restrict__ x,
                                                const float* __restrict__ Wg,
                                                float* __restrict__ out) {
    const int b = blockIdx.x * 256 + threadIdx.x;
    const float4 xv = ((const float4*)x)[b];
    const float xs[4] = {xv.x, xv.y, xv.z, xv.w};

    // encoding columns: [cos(x/2), e^{ix} sin(x/2)]
    float vr[4][2], vi[4][2];
#pragma unroll
    for (int i = 0; i < 4; i++) {
        const float st = __sinf(xs[i] * 0.5f);
        const float ct = __cosf(xs[i] * 0.5f);
        const float sx = __sinf(xs[i]);
        const float cx = __cosf(xs[i]);
        vr[i][0] = ct;      vi[i][0] = 0.0f;
        vr[i][1] = cx * st; vi[i][1] = sx * st;
    }

    // tensor product -> 16 complex amps (wire0 = bit3)
    float w01r[4], w01i[4], w23r[4], w23i[4];
#pragma unroll
    for (int a = 0; a < 2; a++) {
#pragma unroll
        for (int c = 0; c < 2; c++) {
            w01r[a * 2 + c] = vr[0][a] * vr[1][c] - vi[0][a] * vi[1][c];
            w01i[a * 2 + c] = vr[0][a] * vi[1][c] + vi[0][a] * vr[1][c];
            w23r[a * 2 + c] = vr[2][a] * vr[3][c] - vi[2][a] * vi[3][c];
            w23i[a * 2 + c] = vr[2][a] * vi[3][c] + vi[2][a] * vr[3][c];
        }
    }
    float sr[16], si[16];
#pragma unroll
    for (int hi = 0; hi < 4; hi++) {
#pragma unroll
        for (int lo = 0; lo < 4; lo++) {
            sr[hi * 4 + lo] = w01r[hi] * w23r[lo] - w01i[hi] * w23i[lo];
            si[hi * 4 + lo] = w01r[hi] * w23i[lo] + w01i[hi] * w23r[lo];
        }
    }

    // psi = W * psi0 ; <Z_i> accumulated on the fly with compile-time signs.
    const float4* Wv = (const float4*)Wg;  // row j = Wv[j*8 .. j*8+7]
    float z0 = 0.f, z1 = 0.f, z2 = 0.f, z3 = 0.f;
#pragma unroll
    for (int j = 0; j < 16; j++) {
        float pr0 = 0.f, pr1 = 0.f, pi0 = 0.f, pi1 = 0.f;
#pragma unroll
        for (int kk = 0; kk < 8; kk++) {
            const float4 q = Wv[j * 8 + kk];  // (Wr[2kk], Wi[2kk], Wr[2kk+1], Wi[2kk+1])
            const int k = kk * 2;
            pr0 = fmaf(q.x, sr[k], pr0);
            pr0 = fmaf(-q.y, si[k], pr0);
            pi0 = fmaf(q.x, si[k], pi0);
            pi0 = fmaf(q.y, sr[k], pi0);
            pr1 = fmaf(q.z, sr[k + 1], pr1);
            pr1 = fmaf(-q.w, si[k + 1], pr1);
            pi1 = fmaf(q.z, si[k + 1], pi1);
            pi1 = fmaf(q.w, sr[k + 1], pi1);
        }
        const float prr = pr0 + pr1;
        const float pii = pi0 + pi1;
        const float p = prr * prr + pii * pii;
        // wire i sign flips on bit (8>>i) of j
        z0 = (j & 8) ? (z0 - p) : (z0 + p);
        z1 = (j & 4) ? (z1 - p) : (z1 + p);
        z2 = (j & 2) ? (z2 - p) : (z2 + p);
        z3 = (j & 1) ? (z3 - p) : (z3 + p);
    }

    ((float4*)out)[b] = make_float4(z0, z1, z2, z3);
}

extern "C" void kernel_launch(void* const* d_in, const int* in_sizes, int n_in,
                              void* d_out, int out_size, void* d_ws, size_t ws_size,
                              hipStream_t stream) {
    const float* x = (const float*)d_in[0];   // [B,4] fp32
    const float* w = (const float*)d_in[1];   // [5,4,3] fp32
    float* out = (float*)d_out;               // [B,4] fp32
    float* W = (float*)d_ws;                  // 16*16*2 floats = 2 KB
    const int b = in_sizes[0] / 4;

    compose_W<<<1, 64, 0, stream>>>(w, W);
    qmain<<<b / 256, 256, 0, stream>>>(x, W, out);
}